// Round 7
// baseline (3654.779 us; speedup 1.0000x reference)
//
#include <hip/hip_runtime.h>
#include <hip/hip_bf16.h>
#include <cstdint>
#include <cstddef>

// N=30000 nodes, E=480000 edges, HID=256, SW=512, NB=128 bundles of dim 2.
// Householder(2x2) collapses to planar rotation: x=X[1,0]; c=(x^2-1)/(1+x^2), s=2x/(1+x^2).

typedef __attribute__((ext_vector_type(8))) short short8;
typedef __attribute__((ext_vector_type(4))) float f32x4;

__device__ __forceinline__ float gelu_exact(float x) {
  return 0.5f * x * (1.0f + erff(x * 0.7071067811865475f));
}
__device__ __forceinline__ unsigned short f2bf(float f) {
  __hip_bfloat16 b = __float2bfloat16(f);
  return *reinterpret_cast<unsigned short*>(&b);
}
__device__ __forceinline__ float bf2f(unsigned short u) {
  return __uint_as_float((unsigned)u << 16);
}
__device__ __forceinline__ float bflo(unsigned u) { return __uint_as_float(u << 16); }
__device__ __forceinline__ float bfhi(unsigned u) { return __uint_as_float(u & 0xffff0000u); }
__device__ __forceinline__ unsigned packbf(float f0, float f1) {
  return (unsigned)f2bf(f0) | ((unsigned)f2bf(f1) << 16);
}
__device__ __forceinline__ void gload16(const void* g, void* l) {
  __builtin_amdgcn_global_load_lds((const __attribute__((address_space(1))) void*)g,
                                   (__attribute__((address_space(3))) void*)l, 16, 0, 0);
}

// ---------------- CSR build ----------------
__global__ void k_hist(const int* __restrict__ dst, int* __restrict__ deg, int E) {
  int i = blockIdx.x * 256 + threadIdx.x;
  if (i < E) atomicAdd(&deg[dst[i]], 1);
}

__global__ __launch_bounds__(1024)
void k_scan(const int* __restrict__ deg, int* __restrict__ rp, int* __restrict__ cur, int Nn) {
  __shared__ int part[1024];
  int t = threadIdx.x;
  int chunk = (Nn + 1023) >> 10;
  int s0 = t * chunk;
  int e0 = s0 + chunk; if (e0 > Nn) e0 = Nn;
  int s = 0;
  for (int i = s0; i < e0; ++i) s += deg[i];
  part[t] = s;
  __syncthreads();
  for (int off = 1; off < 1024; off <<= 1) {
    int v = (t >= off) ? part[t - off] : 0;
    __syncthreads();
    part[t] += v;
    __syncthreads();
  }
  int base = (t == 0) ? 0 : part[t - 1];
  for (int i = s0; i < e0; ++i) {
    rp[i] = base; cur[i] = base; base += deg[i];
  }
  if (t == 0) rp[Nn] = part[1023];
}

__global__ void k_fill(const int* __restrict__ src, const int* __restrict__ dst,
                       int* __restrict__ cur, int* __restrict__ srcs, int E) {
  int i = blockIdx.x * 256 + threadIdx.x;
  if (i < E) {
    int p = atomicAdd(&cur[dst[i]], 1);
    srcs[p] = src[i];
  }
}

// ---------------- batched weight transpose fp32 [K,N] -> bf16 [N,K] ----------------
__global__ void k_wT(const float* __restrict__ W, unsigned short* __restrict__ Wt, int K, int Nc) {
  const float* Ws = W + (size_t)blockIdx.y * K * Nc;
  unsigned short* Wd = Wt + (size_t)blockIdx.y * K * Nc;
  int idx = blockIdx.x * 256 + threadIdx.x;
  if (idx >= K * Nc) return;
  int k = idx % K, n = idx / K;                       // k fastest -> coalesced writes
  Wd[(size_t)n * K + k] = f2bf(Ws[(size_t)k * Nc + n]);
}

__global__ void k_cast(const float* __restrict__ src, unsigned short* __restrict__ dst, int n) {
  int i = blockIdx.x * 256 + threadIdx.x;
  if (i < n) dst[i] = f2bf(src[i]);
}

// ---------------- bf16 MFMA GEMM (round-2 structure + XCD co-location) ----------------
// C = [R +] act(A @ W + bias), A bf16 row-major (dual-source concat along K),
// Wt = W^T bf16 [Nc, Ktot] row-major. fp32 accumulate.
// 128x128 tile, BK=64, 4 waves, 32 KiB LDS single-buffer -> 5 blocks/CU (TLP hides latency).
// 1D padded grid; decode maps all n-blocks of an A-panel to the SAME XCD (ids = same mod 8)
// so the A-tile is fetched once and L2-hits for the other column blocks.
// RES: 0=none, 1=fp32 residual, 2=bf16 residual.
template<int ACT, int RES, bool DUAL, bool W32, bool WBF>
__global__ __launch_bounds__(256)
void k_mfma(const unsigned short* __restrict__ A1, const unsigned short* __restrict__ A2,
            int K1, int K2,
            const unsigned short* __restrict__ Wt, const float* __restrict__ bias,
            const float* R32, const unsigned short* Rbf,
            float* C32, unsigned short* Cbf, int M, int Nc) {
  const int mb_cnt = (M + 127) >> 7;
  const int nb_cnt = Nc >> 7;
  int u = blockIdx.x;
  int xcd = u & 7;
  int rest = u >> 3;
  int nb = rest % nb_cnt;
  int mb = (rest / nb_cnt) * 8 + xcd;
  if (mb >= mb_cnt) return;
  const int m0 = mb << 7, n0 = nb << 7;

  __shared__ unsigned short As[128 * 64];   // [row][64] bf16, 128B rows, XOR-swizzled segs
  __shared__ unsigned short Bs[128 * 64];
  const int tid = threadIdx.x;
  const int lane = tid & 63, wv = tid >> 6;
  const int wr = (wv >> 1) * 64, wc = (wv & 1) * 64;  // wave's 64x64 subtile
  const int rA = lane & 15, kg = lane >> 4;
  const int Ktot = K1 + K2;

  f32x4 acc[4][4];
#pragma unroll
  for (int m = 0; m < 4; ++m)
#pragma unroll
    for (int n = 0; n < 4; ++n)
#pragma unroll
      for (int r = 0; r < 4; ++r) acc[m][n][r] = 0.f;

  for (int k0 = 0; k0 < Ktot; k0 += 64) {
    const unsigned short* Asrc; int kc, lda;
    if (!DUAL || k0 < K1) { Asrc = A1; kc = k0; lda = K1; }
    else                  { Asrc = A2; kc = k0 - K1; lda = K2; }
    __syncthreads();   // all waves done reading previous tile
    // stage A,B: 1024 16B-chunks each, 4 issues of 256 threads.
    // linear LDS dest; swizzle applied on the GLOBAL source k-segment (involution).
#pragma unroll
    for (int is = 0; is < 4; ++is) {
      int chunk = is * 256 + tid;
      int row = chunk >> 3, seg = chunk & 7;
      int ks = seg ^ (row & 7);
      int gm = m0 + row; gm = gm < M ? gm : M - 1;
      gload16(Asrc + (size_t)gm * lda + kc + ks * 8,
              (char*)As + (size_t)(is * 256 + (wv << 6)) * 16);
      gload16(Wt + (size_t)(n0 + row) * Ktot + k0 + ks * 8,
              (char*)Bs + (size_t)(is * 256 + (wv << 6)) * 16);
    }
    __syncthreads();   // staged data visible (syncthreads drains vmcnt)
#pragma unroll
    for (int kk = 0; kk < 2; ++kk) {
      short8 af[4], bfr[4];
#pragma unroll
      for (int m = 0; m < 4; ++m) {
        int row = wr + m * 16 + rA;
        int ks = (kk * 4 + kg) ^ (row & 7);
        af[m] = *reinterpret_cast<const short8*>((const char*)As + row * 128 + ks * 16);
      }
#pragma unroll
      for (int n = 0; n < 4; ++n) {
        int col = wc + n * 16 + rA;
        int ks = (kk * 4 + kg) ^ (col & 7);
        bfr[n] = *reinterpret_cast<const short8*>((const char*)Bs + col * 128 + ks * 16);
      }
#pragma unroll
      for (int m = 0; m < 4; ++m)
#pragma unroll
        for (int n = 0; n < 4; ++n)
          acc[m][n] = __builtin_amdgcn_mfma_f32_16x16x32_bf16(af[m], bfr[n], acc[m][n], 0, 0, 0);
    }
  }

  // epilogue: C/D layout col=lane&15, row=(lane>>4)*4+reg  [m89]
#pragma unroll
  for (int m = 0; m < 4; ++m) {
    int gr0 = m0 + wr + m * 16 + kg * 4;
#pragma unroll
    for (int n = 0; n < 4; ++n) {
      int gc = n0 + wc + n * 16 + rA;
      float bv = bias[gc];
#pragma unroll
      for (int r = 0; r < 4; ++r) {
        int gr = gr0 + r;
        if (gr < M) {
          float v = acc[m][n][r] + bv;
          if (ACT == 1) v = gelu_exact(v);
          if (RES == 1) v += R32[(size_t)gr * Nc + gc];
          if (RES == 2) v += bf2f(Rbf[(size_t)gr * Nc + gc]);
          if (W32) C32[(size_t)gr * Nc + gc] = v;
          if (WBF) Cbf[(size_t)gr * Nc + gc] = f2bf(v);
        }
      }
    }
  }
}

// ---------------- column-sliced mean aggregation (XCD-affine L2 locality) ----------------
// Block u handles column slice (u & (SL-1)) of 64 columns; blocks round-robin XCDs, so
// all gathers on XCD x touch only that slice (~3.84 MB) -> L2-resident.
// One wave per node per slice; lane = column; grid-strided over nodes.
// ROT (W=256): fuse msg = O^T * mean via lane-pair shuffle (col pair 2b,2b+1 = lanes 2i,2i+1).
template<int W, int LSL, bool ROT>
__global__ __launch_bounds__(256)
void k_aggs(const unsigned short* __restrict__ X, const int* __restrict__ rp,
            const int* __restrict__ srcs, const float* __restrict__ o,
            unsigned short* __restrict__ out, int Nn) {
  constexpr int SL = 1 << LSL;
  static_assert(W / SL == 64, "64 columns per slice");
  const int u = blockIdx.x;
  const int sl = u & (SL - 1);
  const int g = u >> LSL;
  const int ngrp = (int)(gridDim.x >> LSL);
  const int wv = threadIdx.x >> 6, lane = threadIdx.x & 63;
  const int c = sl * 64 + lane;
  const int stride = ngrp * 4;

  for (int v = g * 4 + wv; v < Nn; v += stride) {
    int beg = __builtin_nontemporal_load(rp + v);
    int end = __builtin_nontemporal_load(rp + v + 1);
    float a = 0.f;
    int e = beg;
    for (; e + 4 <= end; e += 4) {
      int s0 = __builtin_nontemporal_load(srcs + e);
      int s1 = __builtin_nontemporal_load(srcs + e + 1);
      int s2 = __builtin_nontemporal_load(srcs + e + 2);
      int s3 = __builtin_nontemporal_load(srcs + e + 3);
      float v0 = bf2f(X[(size_t)s0 * W + c]);
      float v1 = bf2f(X[(size_t)s1 * W + c]);
      float v2 = bf2f(X[(size_t)s2 * W + c]);
      float v3 = bf2f(X[(size_t)s3 * W + c]);
      a += (v0 + v1) + (v2 + v3);
    }
    for (; e < end; ++e) {
      int s0 = __builtin_nontemporal_load(srcs + e);
      a += bf2f(X[(size_t)s0 * W + c]);
    }
    float inv = (end > beg) ? 1.0f / (float)(end - beg) : 0.0f;
    a *= inv;
    if (ROT) {
      float ap = __shfl_xor(a, 1);
      float2 cs = *reinterpret_cast<const float2*>(o + (size_t)v * 256 + (c & ~1));
      // m_even = c*a0 - s*a1 ; m_odd = s*a0 + c*a1
      a = (lane & 1) ? (cs.y * ap + cs.x * a) : (cs.x * a - cs.y * ap);
    }
    __builtin_nontemporal_store(f2bf(a), out + (size_t)v * W + c);
  }
}

// ---------------- Householder(2x2) -> rotation params (nr is bf16) ----------------
__global__ void k_oparams(const unsigned short* __restrict__ nr, float* __restrict__ o, int total) {
  int idx = blockIdx.x * 256 + threadIdx.x;
  if (idx >= total) return;
  float x = bf2f(nr[(size_t)idx * 4 + 2]);
  float inv = 1.0f / (1.0f + x * x);
  o[(size_t)idx * 2]     = (x * x - 1.0f) * inv;
  o[(size_t)idx * 2 + 1] = 2.0f * x * inv;
}

// ---------------- LayerNorm + rotate-into-frame; bf16 outputs ----------------
__global__ __launch_bounds__(256)
void k_ln_rot(const float* __restrict__ h, const float* __restrict__ o,
              const float* __restrict__ g, const float* __restrict__ b,
              unsigned short* __restrict__ hn, unsigned short* __restrict__ y, int Nn) {
  int wid = (blockIdx.x * 256 + threadIdx.x) >> 6;
  int lane = threadIdx.x & 63;
  if (wid >= Nn) return;
  float4 v = reinterpret_cast<const float4*>(h + (size_t)wid * 256)[lane];
  float s = v.x + v.y + v.z + v.w;
  float ss = v.x * v.x + v.y * v.y + v.z * v.z + v.w * v.w;
#pragma unroll
  for (int off = 1; off < 64; off <<= 1) { s += __shfl_xor(s, off); ss += __shfl_xor(ss, off); }
  float mean = s * (1.0f / 256.0f);
  float var = ss * (1.0f / 256.0f) - mean * mean;
  float rs = rsqrtf(var + 1e-5f);
  float4 gg = reinterpret_cast<const float4*>(g)[lane];
  float4 bb = reinterpret_cast<const float4*>(b)[lane];
  float h0 = (v.x - mean) * rs * gg.x + bb.x;
  float h1 = (v.y - mean) * rs * gg.y + bb.y;
  float h2 = (v.z - mean) * rs * gg.z + bb.z;
  float h3 = (v.w - mean) * rs * gg.w + bb.w;
  uint2 hv; hv.x = packbf(h0, h1); hv.y = packbf(h2, h3);
  *reinterpret_cast<uint2*>(hn + (size_t)wid * 256 + lane * 4) = hv;
  float4 oc = *reinterpret_cast<const float4*>(o + (size_t)wid * 256 + lane * 4); // c0,s0,c1,s1
  float y0 =  oc.x * h0 + oc.y * h1;
  float y1 = -oc.y * h0 + oc.x * h1;
  float y2 =  oc.z * h2 + oc.w * h3;
  float y3 = -oc.w * h2 + oc.z * h3;
  uint2 yv; yv.x = packbf(y0, y1); yv.y = packbf(y2, y3);
  *reinterpret_cast<uint2*>(y + (size_t)wid * 256 + lane * 4) = yv;
}

// ---------------- final: out = LN(h) @ w_out + b_out ----------------
__global__ __launch_bounds__(256)
void k_final(const float* __restrict__ h, const float* __restrict__ g,
             const float* __restrict__ b, const float* __restrict__ wout,
             const float* __restrict__ bout, float* __restrict__ out, int Nn) {
  int wid = (blockIdx.x * 256 + threadIdx.x) >> 6;
  int lane = threadIdx.x & 63;
  if (wid >= Nn) return;
  float4 v = reinterpret_cast<const float4*>(h + (size_t)wid * 256)[lane];
  float s = v.x + v.y + v.z + v.w;
  float ss = v.x * v.x + v.y * v.y + v.z * v.z + v.w * v.w;
#pragma unroll
  for (int off = 1; off < 64; off <<= 1) { s += __shfl_xor(s, off); ss += __shfl_xor(ss, off); }
  float mean = s * (1.0f / 256.0f);
  float var = ss * (1.0f / 256.0f) - mean * mean;
  float rs = rsqrtf(var + 1e-5f);
  float4 gg = reinterpret_cast<const float4*>(g)[lane];
  float4 bb = reinterpret_cast<const float4*>(b)[lane];
  float hv[4];
  hv[0] = (v.x - mean) * rs * gg.x + bb.x;
  hv[1] = (v.y - mean) * rs * gg.y + bb.y;
  hv[2] = (v.z - mean) * rs * gg.z + bb.z;
  hv[3] = (v.w - mean) * rs * gg.w + bb.w;
  int c0 = lane * 4;
  float dots[5];
#pragma unroll
  for (int j = 0; j < 5; ++j) {
    float p = hv[0] * wout[(size_t)(c0 + 0) * 5 + j] + hv[1] * wout[(size_t)(c0 + 1) * 5 + j]
            + hv[2] * wout[(size_t)(c0 + 2) * 5 + j] + hv[3] * wout[(size_t)(c0 + 3) * 5 + j];
#pragma unroll
    for (int off = 1; off < 64; off <<= 1) p += __shfl_xor(p, off);
    dots[j] = p;
  }
  if (lane == 0) {
#pragma unroll
    for (int j = 0; j < 5; ++j) out[(size_t)wid * 5 + j] = dots[j] + bout[j];
  }
}

// ---------------- host-side launch ----------------
extern "C" void kernel_launch(void* const* d_in, const int* in_sizes, int n_in,
                              void* d_out, int out_size, void* d_ws, size_t ws_size,
                              hipStream_t stream) {
  const float* x       = (const float*)d_in[0];
  const int*   ei      = (const int*)  d_in[1];
  const float* w_in    = (const float*)d_in[2];
  const float* b_in    = (const float*)d_in[3];
  const float* se_in_w = (const float*)d_in[4];
  const float* se_in_b = (const float*)d_in[5];
  const float* sage_w1 = (const float*)d_in[6];
  const float* sage_b1 = (const float*)d_in[7];
  const float* sage_w2 = (const float*)d_in[8];
  const float* sage_b2 = (const float*)d_in[9];
  const float* se_out_w= (const float*)d_in[10];
  const float* se_out_b= (const float*)d_in[11];
  const float* enc_w1  = (const float*)d_in[12];
  const float* enc_b1  = (const float*)d_in[13];
  const float* enc_w2  = (const float*)d_in[14];
  const float* enc_b2  = (const float*)d_in[15];
  const float* ln_g    = (const float*)d_in[16];
  const float* ln_b    = (const float*)d_in[17];
  const float* bdl_w1  = (const float*)d_in[18];
  const float* bdl_b1  = (const float*)d_in[19];
  const float* bdl_w2  = (const float*)d_in[20];
  const float* bdl_b2  = (const float*)d_in[21];
  const float* oln_g   = (const float*)d_in[22];
  const float* oln_b   = (const float*)d_in[23];
  const float* w_out   = (const float*)d_in[24];
  const float* b_out   = (const float*)d_in[25];
  float* out = (float*)d_out;

  const int HID = 256, SW = 512;
  const int N = in_sizes[0] / HID;   // 30000
  const int E = in_sizes[1] / 2;     // 480000

  // ---- workspace layout (~185 MB) ----
  float* ws = (float*)d_ws;
  float* h32 = ws;                              // [N,256] fp32 residual carrier (outer)
  float* o   = h32 + (size_t)N * HID;           // [N,256] rotation (c,s)*128
  unsigned short* h_bf = (unsigned short*)(o + (size_t)N * HID);  // [N,256]
  unsigned short* z_bf = h_bf + (size_t)N * HID;                  // [N,512] bf16 z carrier
  unsigned short* t_bf = z_bf + (size_t)N * SW;                   // [N,512]
  unsigned short* u_bf = t_bf + (size_t)N * SW;                   // [N,512]
  // weight transposes (bf16 [N,K])
  unsigned short* wts = u_bf + (size_t)N * SW;
  size_t off = 0;
  unsigned short* wt_in    = wts + off; off += 256 * 256;
  unsigned short* wt_se_in = wts + off; off += 512 * 256;
  unsigned short* wt_sage1 = wts + off; off += (size_t)5 * 512 * 1024;
  unsigned short* wt_sage2 = wts + off; off += (size_t)5 * 512 * 512;
  unsigned short* wt_se_out= wts + off; off += 512 * 512;
  unsigned short* wt_enc1  = wts + off; off += (size_t)2 * 512 * 512;
  unsigned short* wt_enc2  = wts + off; off += (size_t)2 * 512 * 512;
  unsigned short* wt_bdl1  = wts + off; off += (size_t)2 * 256 * 512;
  unsigned short* wt_bdl2  = wts + off; off += (size_t)2 * 256 * 256;
  int* deg  = (int*)(wts + off);
  int* rp   = deg + N;
  int* cur  = rp + N + 1;
  int* srcs = cur + N;
  size_t need = (size_t)((char*)(srcs + E) - (char*)d_ws);
  if (ws_size < need) return;

  // aliases (lifetime-disjoint)
  unsigned short* xbf = u_bf;                   // x cast, consumed by first GEMM
  unsigned short* hn  = z_bf;                   // after z consumed by se_out
  unsigned short* y   = z_bf + (size_t)N * HID;
  unsigned short* msg = t_bf;                   // nr consumed by k_oparams first
  unsigned short* g2  = u_bf;

  const int* esrc = ei;
  const int* edst = ei + E;

  auto cdiv = [](int a, int b) { return (a + b - 1) / b; };
  dim3 blk(256);
  int mb_cnt = cdiv(N, 128);                    // 235
  int mgrp = cdiv(mb_cnt, 8);                   // 30
  int g_g256 = mgrp * 8 * 2;                    // Nc=256 -> 480 blocks (padded)
  int g_g512 = mgrp * 8 * 4;                    // Nc=512 -> 960 blocks (padded)
  int gw = cdiv(N * 64, 256);
  int g_agg512 = 8 * 940;                       // 8 slices x 940 node-groups
  int g_agg256 = 4 * 940;                       // 4 slices

  // ---- CSR build ----
  hipMemsetAsync(deg, 0, sizeof(int) * N, stream);
  k_hist<<<cdiv(E, 256), blk, 0, stream>>>(edst, deg, E);
  k_scan<<<1, 1024, 0, stream>>>(deg, rp, cur, N);
  k_fill<<<cdiv(E, 256), blk, 0, stream>>>(esrc, edst, cur, srcs, E);

  // ---- weight transposes to bf16 (batched over blockIdx.y) ----
  auto wT = [&](const float* W, unsigned short* Wt, int K, int Nc, int cnt) {
    k_wT<<<dim3(cdiv(K * Nc, 256), cnt), blk, 0, stream>>>(W, Wt, K, Nc);
  };
  wT(w_in, wt_in, 256, 256, 1);
  wT(se_in_w, wt_se_in, 256, 512, 1);
  wT(sage_w1, wt_sage1, 1024, 512, 5);
  wT(sage_w2, wt_sage2, 512, 512, 5);
  wT(se_out_w, wt_se_out, 512, 512, 1);
  wT(enc_w1, wt_enc1, 512, 512, 2);
  wT(enc_w2, wt_enc2, 512, 512, 2);
  wT(bdl_w1, wt_bdl1, 512, 256, 2);
  wT(bdl_w2, wt_bdl2, 256, 256, 2);
  k_cast<<<cdiv(N * HID, 256), blk, 0, stream>>>(x, xbf, N * HID);

  // ---- h = gelu(x @ w_in + b_in) : fp32 + bf16 ----
  k_mfma<1, 0, false, true, true><<<g_g256, blk, 0, stream>>>(
      xbf, nullptr, 256, 0, wt_in, b_in, nullptr, nullptr, h32, h_bf, N, 256);

  for (int k = 0; k < 2; ++k) {
    // z = gelu(h @ se_in_w + b)   (bf16 carrier)
    k_mfma<1, 0, false, false, true><<<g_g512, blk, 0, stream>>>(
        h_bf, nullptr, 256, 0, wt_se_in, se_in_b, nullptr, nullptr, nullptr, z_bf, N, 512);
    for (int i = 0; i < 5; ++i) {
      k_aggs<512, 3, false><<<g_agg512, blk, 0, stream>>>(z_bf, rp, srcs, nullptr, t_bf, N);
      k_mfma<1, 0, true, false, true><<<g_g512, blk, 0, stream>>>(
          z_bf, t_bf, 512, 512, wt_sage1 + (size_t)i * 512 * 1024,
          sage_b1 + (size_t)i * SW, nullptr, nullptr, nullptr, u_bf, N, 512);
      k_mfma<0, 2, false, false, true><<<g_g512, blk, 0, stream>>>(
          u_bf, nullptr, 512, 0, wt_sage2 + (size_t)i * 512 * 512,
          sage_b2 + (size_t)i * SW, nullptr, z_bf, nullptr, z_bf, N, 512);
    }
    // enc = z @ se_out_w + b
    k_mfma<0, 0, false, false, true><<<g_g512, blk, 0, stream>>>(
        z_bf, nullptr, 512, 0, wt_se_out, se_out_b, nullptr, nullptr, nullptr, t_bf, N, 512);
    // nr = gelu(enc @ enc_w1 + b) @ enc_w2 + b
    k_mfma<1, 0, false, false, true><<<g_g512, blk, 0, stream>>>(
        t_bf, nullptr, 512, 0, wt_enc1 + (size_t)k * 512 * 512,
        enc_b1 + (size_t)k * SW, nullptr, nullptr, nullptr, u_bf, N, 512);
    k_mfma<0, 0, false, false, true><<<g_g512, blk, 0, stream>>>(
        u_bf, nullptr, 512, 0, wt_enc2 + (size_t)k * 512 * 512,
        enc_b2 + (size_t)k * SW, nullptr, nullptr, nullptr, t_bf, N, 512);
    // rotation params; hn=LN(h), y=O@hn; msg=O^T@mean(y)
    k_oparams<<<cdiv(N * 128, 256), blk, 0, stream>>>(t_bf, o, N * 128);
    k_ln_rot<<<gw, blk, 0, stream>>>(h32, o, ln_g + (size_t)k * HID, ln_b + (size_t)k * HID, hn, y, N);
    k_aggs<256, 2, true><<<g_agg256, blk, 0, stream>>>(y, rp, srcs, o, msg, N);
    // h = h + gelu([hn|msg] @ bdl_w1 + b1) @ bdl_w2 + b2
    k_mfma<1, 0, true, false, true><<<g_g256, blk, 0, stream>>>(
        hn, msg, 256, 256, wt_bdl1 + (size_t)k * 256 * 512,
        bdl_b1 + (size_t)k * HID, nullptr, nullptr, nullptr, g2, N, 256);
    k_mfma<0, 1, false, true, true><<<g_g256, blk, 0, stream>>>(
        g2, nullptr, 256, 0, wt_bdl2 + (size_t)k * 256 * 256,
        bdl_b2 + (size_t)k * HID, h32, nullptr, h32, h_bf, N, 256);
  }

  k_final<<<gw, blk, 0, stream>>>(h32, oln_g, oln_b, w_out, b_out, out, N);
}

// Round 8
// 2864.320 us; speedup vs baseline: 1.2760x; 1.2760x over previous
//
#include <hip/hip_runtime.h>
#include <hip/hip_bf16.h>
#include <cstdint>
#include <cstddef>

// N=30000 nodes, E=480000 edges, HID=256, SW=512, NB=128 bundles of dim 2.
// Householder(2x2) collapses to planar rotation: x=X[1,0]; c=(x^2-1)/(1+x^2), s=2x/(1+x^2).

typedef __attribute__((ext_vector_type(8))) short short8;
typedef __attribute__((ext_vector_type(4))) float f32x4;

__device__ __forceinline__ float gelu_exact(float x) {
  return 0.5f * x * (1.0f + erff(x * 0.7071067811865475f));
}
__device__ __forceinline__ unsigned short f2bf(float f) {
  __hip_bfloat16 b = __float2bfloat16(f);
  return *reinterpret_cast<unsigned short*>(&b);
}
__device__ __forceinline__ float bf2f(unsigned short u) {
  return __uint_as_float((unsigned)u << 16);
}
__device__ __forceinline__ float bflo(unsigned u) { return __uint_as_float(u << 16); }
__device__ __forceinline__ float bfhi(unsigned u) { return __uint_as_float(u & 0xffff0000u); }
__device__ __forceinline__ unsigned packbf(float f0, float f1) {
  return (unsigned)f2bf(f0) | ((unsigned)f2bf(f1) << 16);
}
__device__ __forceinline__ void gload16(const void* g, void* l) {
  __builtin_amdgcn_global_load_lds((const __attribute__((address_space(1))) void*)g,
                                   (__attribute__((address_space(3))) void*)l, 16, 0, 0);
}

// ---------------- CSR build ----------------
__global__ void k_hist(const int* __restrict__ dst, int* __restrict__ deg, int E) {
  int i = blockIdx.x * 256 + threadIdx.x;
  if (i < E) atomicAdd(&deg[dst[i]], 1);
}

__global__ __launch_bounds__(1024)
void k_scan(const int* __restrict__ deg, int* __restrict__ rp, int* __restrict__ cur, int Nn) {
  __shared__ int part[1024];
  int t = threadIdx.x;
  int chunk = (Nn + 1023) >> 10;
  int s0 = t * chunk;
  int e0 = s0 + chunk; if (e0 > Nn) e0 = Nn;
  int s = 0;
  for (int i = s0; i < e0; ++i) s += deg[i];
  part[t] = s;
  __syncthreads();
  for (int off = 1; off < 1024; off <<= 1) {
    int v = (t >= off) ? part[t - off] : 0;
    __syncthreads();
    part[t] += v;
    __syncthreads();
  }
  int base = (t == 0) ? 0 : part[t - 1];
  for (int i = s0; i < e0; ++i) {
    rp[i] = base; cur[i] = base; base += deg[i];
  }
  if (t == 0) rp[Nn] = part[1023];
}

__global__ void k_fill(const int* __restrict__ src, const int* __restrict__ dst,
                       int* __restrict__ cur, int* __restrict__ srcs, int E) {
  int i = blockIdx.x * 256 + threadIdx.x;
  if (i < E) {
    int p = atomicAdd(&cur[dst[i]], 1);
    srcs[p] = src[i];
  }
}

// ---------------- batched weight transpose fp32 [K,N] -> bf16 [N,K] ----------------
__global__ void k_wT(const float* __restrict__ W, unsigned short* __restrict__ Wt, int K, int Nc) {
  const float* Ws = W + (size_t)blockIdx.y * K * Nc;
  unsigned short* Wd = Wt + (size_t)blockIdx.y * K * Nc;
  int idx = blockIdx.x * 256 + threadIdx.x;
  if (idx >= K * Nc) return;
  int k = idx % K, n = idx / K;                       // k fastest -> coalesced writes
  Wd[(size_t)n * K + k] = f2bf(Ws[(size_t)k * Nc + n]);
}

__global__ void k_cast(const float* __restrict__ src, unsigned short* __restrict__ dst, int n) {
  int i = blockIdx.x * 256 + threadIdx.x;
  if (i < n) dst[i] = f2bf(src[i]);
}

// ---------------- bf16 MFMA GEMM (round-2 structure + XCD co-location) ----------------
// C = [R +] act(A @ W + bias), A bf16 row-major (dual-source concat along K),
// Wt = W^T bf16 [Nc, Ktot] row-major. fp32 accumulate.
// 128x128 tile, BK=64, 4 waves, 32 KiB LDS single-buffer -> 5 blocks/CU (TLP hides latency).
// 1D padded grid; decode maps all n-blocks of an A-panel to the SAME XCD (ids = same mod 8)
// so the A-tile is fetched once and L2-hits for the other column blocks.
// RES: 0=none, 1=fp32 residual, 2=bf16 residual.
template<int ACT, int RES, bool DUAL, bool W32, bool WBF>
__global__ __launch_bounds__(256)
void k_mfma(const unsigned short* __restrict__ A1, const unsigned short* __restrict__ A2,
            int K1, int K2,
            const unsigned short* __restrict__ Wt, const float* __restrict__ bias,
            const float* R32, const unsigned short* Rbf,
            float* C32, unsigned short* Cbf, int M, int Nc) {
  const int mb_cnt = (M + 127) >> 7;
  const int nb_cnt = Nc >> 7;
  int u = blockIdx.x;
  int xcd = u & 7;
  int rest = u >> 3;
  int nb = rest % nb_cnt;
  int mb = (rest / nb_cnt) * 8 + xcd;
  if (mb >= mb_cnt) return;
  const int m0 = mb << 7, n0 = nb << 7;

  __shared__ unsigned short As[128 * 64];   // [row][64] bf16, 128B rows, XOR-swizzled segs
  __shared__ unsigned short Bs[128 * 64];
  const int tid = threadIdx.x;
  const int lane = tid & 63, wv = tid >> 6;
  const int wr = (wv >> 1) * 64, wc = (wv & 1) * 64;  // wave's 64x64 subtile
  const int rA = lane & 15, kg = lane >> 4;
  const int Ktot = K1 + K2;

  f32x4 acc[4][4];
#pragma unroll
  for (int m = 0; m < 4; ++m)
#pragma unroll
    for (int n = 0; n < 4; ++n)
#pragma unroll
      for (int r = 0; r < 4; ++r) acc[m][n][r] = 0.f;

  for (int k0 = 0; k0 < Ktot; k0 += 64) {
    const unsigned short* Asrc; int kc, lda;
    if (!DUAL || k0 < K1) { Asrc = A1; kc = k0; lda = K1; }
    else                  { Asrc = A2; kc = k0 - K1; lda = K2; }
    __syncthreads();   // all waves done reading previous tile
    // stage A,B: 1024 16B-chunks each, 4 issues of 256 threads.
    // linear LDS dest; swizzle applied on the GLOBAL source k-segment (involution).
#pragma unroll
    for (int is = 0; is < 4; ++is) {
      int chunk = is * 256 + tid;
      int row = chunk >> 3, seg = chunk & 7;
      int ks = seg ^ (row & 7);
      int gm = m0 + row; gm = gm < M ? gm : M - 1;
      gload16(Asrc + (size_t)gm * lda + kc + ks * 8,
              (char*)As + (size_t)(is * 256 + (wv << 6)) * 16);
      gload16(Wt + (size_t)(n0 + row) * Ktot + k0 + ks * 8,
              (char*)Bs + (size_t)(is * 256 + (wv << 6)) * 16);
    }
    __syncthreads();   // staged data visible (syncthreads drains vmcnt)
#pragma unroll
    for (int kk = 0; kk < 2; ++kk) {
      short8 af[4], bfr[4];
#pragma unroll
      for (int m = 0; m < 4; ++m) {
        int row = wr + m * 16 + rA;
        int ks = (kk * 4 + kg) ^ (row & 7);
        af[m] = *reinterpret_cast<const short8*>((const char*)As + row * 128 + ks * 16);
      }
#pragma unroll
      for (int n = 0; n < 4; ++n) {
        int col = wc + n * 16 + rA;
        int ks = (kk * 4 + kg) ^ (col & 7);
        bfr[n] = *reinterpret_cast<const short8*>((const char*)Bs + col * 128 + ks * 16);
      }
#pragma unroll
      for (int m = 0; m < 4; ++m)
#pragma unroll
        for (int n = 0; n < 4; ++n)
          acc[m][n] = __builtin_amdgcn_mfma_f32_16x16x32_bf16(af[m], bfr[n], acc[m][n], 0, 0, 0);
    }
  }

  // epilogue: C/D layout col=lane&15, row=(lane>>4)*4+reg  [m89]
#pragma unroll
  for (int m = 0; m < 4; ++m) {
    int gr0 = m0 + wr + m * 16 + kg * 4;
#pragma unroll
    for (int n = 0; n < 4; ++n) {
      int gc = n0 + wc + n * 16 + rA;
      float bv = bias[gc];
#pragma unroll
      for (int r = 0; r < 4; ++r) {
        int gr = gr0 + r;
        if (gr < M) {
          float v = acc[m][n][r] + bv;
          if (ACT == 1) v = gelu_exact(v);
          if (RES == 1) v += R32[(size_t)gr * Nc + gc];
          if (RES == 2) v += bf2f(Rbf[(size_t)gr * Nc + gc]);
          if (W32) C32[(size_t)gr * Nc + gc] = v;
          if (WBF) Cbf[(size_t)gr * Nc + gc] = f2bf(v);
        }
      }
    }
  }
}

// ---------------- XCD-affine sliced mean aggregation, 16B/lane ----------------
// Block u owns column slice (u & (SL-1)) of 64 cols; blocks round-robin XCDs so each
// XCD's gathers touch only its ~3.84 MB slice -> L2-resident (FETCH check: ~31 MB).
// Wave layout: lane = (edge-group grp=lane>>3, chunk sub=lane&7); per iteration the wave
// gathers 8 edges x 128B slice at 16B/lane (1 KB/instruction, round-6 issue efficiency).
// Cross-edge reduce: shfl_xor offsets 8/16/32. ROT: lane-local (4 whole bundles/lane).
template<int W, int LSL, bool ROT>
__global__ __launch_bounds__(256)
void k_agg2(const unsigned short* __restrict__ X, const int* __restrict__ rp,
            const int* __restrict__ srcs, const float* __restrict__ o,
            unsigned short* __restrict__ out, int Nn) {
  constexpr int SL = 1 << LSL;
  static_assert(W / SL == 64, "64 columns per slice");
  const int u = blockIdx.x;
  const int sl = u & (SL - 1);
  const int g = u >> LSL;
  const int ngrp = (int)(gridDim.x >> LSL);
  const int wv = threadIdx.x >> 6, lane = threadIdx.x & 63;
  const int grp = lane >> 3, sub = lane & 7;
  const int c0 = sl * 64 + sub * 8;            // this lane's 8 columns
  const int stride = ngrp * 4;

  for (int v = g * 4 + wv; v < Nn; v += stride) {
    int beg = rp[v], end = rp[v + 1];
    float a[8];
#pragma unroll
    for (int i = 0; i < 8; ++i) a[i] = 0.f;
    for (int e = beg; e < end; e += 8) {
      int ei = e + grp;
      uint4 vv = make_uint4(0u, 0u, 0u, 0u);
      if (ei < end) {
        int s = srcs[ei];
        vv = *reinterpret_cast<const uint4*>(X + (size_t)s * W + c0);
      }
      a[0] += bflo(vv.x); a[1] += bfhi(vv.x);
      a[2] += bflo(vv.y); a[3] += bfhi(vv.y);
      a[4] += bflo(vv.z); a[5] += bfhi(vv.z);
      a[6] += bflo(vv.w); a[7] += bfhi(vv.w);
    }
    // sum over the 8 edge-groups
#pragma unroll
    for (int off = 8; off < 64; off <<= 1)
#pragma unroll
      for (int i = 0; i < 8; ++i) a[i] += __shfl_xor(a[i], off);
    float inv = (end > beg) ? 1.0f / (float)(end - beg) : 0.0f;
#pragma unroll
    for (int i = 0; i < 8; ++i) a[i] *= inv;
    if (ROT) {
      // msg = O^T * mean; bundles are column pairs, fully lane-local here.
      float4 cs0 = *reinterpret_cast<const float4*>(o + (size_t)v * 256 + c0);
      float4 cs1 = *reinterpret_cast<const float4*>(o + (size_t)v * 256 + c0 + 4);
      float t0 = cs0.x * a[0] - cs0.y * a[1];
      float t1 = cs0.y * a[0] + cs0.x * a[1];
      float t2 = cs0.z * a[2] - cs0.w * a[3];
      float t3 = cs0.w * a[2] + cs0.z * a[3];
      float t4 = cs1.x * a[4] - cs1.y * a[5];
      float t5 = cs1.y * a[4] + cs1.x * a[5];
      float t6 = cs1.z * a[6] - cs1.w * a[7];
      float t7 = cs1.w * a[6] + cs1.z * a[7];
      a[0] = t0; a[1] = t1; a[2] = t2; a[3] = t3;
      a[4] = t4; a[5] = t5; a[6] = t6; a[7] = t7;
    }
    if (grp == 0) {
      uint4 rv;
      rv.x = packbf(a[0], a[1]); rv.y = packbf(a[2], a[3]);
      rv.z = packbf(a[4], a[5]); rv.w = packbf(a[6], a[7]);
      *reinterpret_cast<uint4*>(out + (size_t)v * W + c0) = rv;
    }
  }
}

// ---------------- Householder(2x2) -> rotation params (nr is bf16) ----------------
__global__ void k_oparams(const unsigned short* __restrict__ nr, float* __restrict__ o, int total) {
  int idx = blockIdx.x * 256 + threadIdx.x;
  if (idx >= total) return;
  float x = bf2f(nr[(size_t)idx * 4 + 2]);
  float inv = 1.0f / (1.0f + x * x);
  o[(size_t)idx * 2]     = (x * x - 1.0f) * inv;
  o[(size_t)idx * 2 + 1] = 2.0f * x * inv;
}

// ---------------- LayerNorm + rotate-into-frame; bf16 outputs ----------------
__global__ __launch_bounds__(256)
void k_ln_rot(const float* __restrict__ h, const float* __restrict__ o,
              const float* __restrict__ g, const float* __restrict__ b,
              unsigned short* __restrict__ hn, unsigned short* __restrict__ y, int Nn) {
  int wid = (blockIdx.x * 256 + threadIdx.x) >> 6;
  int lane = threadIdx.x & 63;
  if (wid >= Nn) return;
  float4 v = reinterpret_cast<const float4*>(h + (size_t)wid * 256)[lane];
  float s = v.x + v.y + v.z + v.w;
  float ss = v.x * v.x + v.y * v.y + v.z * v.z + v.w * v.w;
#pragma unroll
  for (int off = 1; off < 64; off <<= 1) { s += __shfl_xor(s, off); ss += __shfl_xor(ss, off); }
  float mean = s * (1.0f / 256.0f);
  float var = ss * (1.0f / 256.0f) - mean * mean;
  float rs = rsqrtf(var + 1e-5f);
  float4 gg = reinterpret_cast<const float4*>(g)[lane];
  float4 bb = reinterpret_cast<const float4*>(b)[lane];
  float h0 = (v.x - mean) * rs * gg.x + bb.x;
  float h1 = (v.y - mean) * rs * gg.y + bb.y;
  float h2 = (v.z - mean) * rs * gg.z + bb.z;
  float h3 = (v.w - mean) * rs * gg.w + bb.w;
  uint2 hv; hv.x = packbf(h0, h1); hv.y = packbf(h2, h3);
  *reinterpret_cast<uint2*>(hn + (size_t)wid * 256 + lane * 4) = hv;
  float4 oc = *reinterpret_cast<const float4*>(o + (size_t)wid * 256 + lane * 4); // c0,s0,c1,s1
  float y0 =  oc.x * h0 + oc.y * h1;
  float y1 = -oc.y * h0 + oc.x * h1;
  float y2 =  oc.z * h2 + oc.w * h3;
  float y3 = -oc.w * h2 + oc.z * h3;
  uint2 yv; yv.x = packbf(y0, y1); yv.y = packbf(y2, y3);
  *reinterpret_cast<uint2*>(y + (size_t)wid * 256 + lane * 4) = yv;
}

// ---------------- final: out = LN(h) @ w_out + b_out ----------------
__global__ __launch_bounds__(256)
void k_final(const float* __restrict__ h, const float* __restrict__ g,
             const float* __restrict__ b, const float* __restrict__ wout,
             const float* __restrict__ bout, float* __restrict__ out, int Nn) {
  int wid = (blockIdx.x * 256 + threadIdx.x) >> 6;
  int lane = threadIdx.x & 63;
  if (wid >= Nn) return;
  float4 v = reinterpret_cast<const float4*>(h + (size_t)wid * 256)[lane];
  float s = v.x + v.y + v.z + v.w;
  float ss = v.x * v.x + v.y * v.y + v.z * v.z + v.w * v.w;
#pragma unroll
  for (int off = 1; off < 64; off <<= 1) { s += __shfl_xor(s, off); ss += __shfl_xor(ss, off); }
  float mean = s * (1.0f / 256.0f);
  float var = ss * (1.0f / 256.0f) - mean * mean;
  float rs = rsqrtf(var + 1e-5f);
  float4 gg = reinterpret_cast<const float4*>(g)[lane];
  float4 bb = reinterpret_cast<const float4*>(b)[lane];
  float hv[4];
  hv[0] = (v.x - mean) * rs * gg.x + bb.x;
  hv[1] = (v.y - mean) * rs * gg.y + bb.y;
  hv[2] = (v.z - mean) * rs * gg.z + bb.z;
  hv[3] = (v.w - mean) * rs * gg.w + bb.w;
  int c0 = lane * 4;
  float dots[5];
#pragma unroll
  for (int j = 0; j < 5; ++j) {
    float p = hv[0] * wout[(size_t)(c0 + 0) * 5 + j] + hv[1] * wout[(size_t)(c0 + 1) * 5 + j]
            + hv[2] * wout[(size_t)(c0 + 2) * 5 + j] + hv[3] * wout[(size_t)(c0 + 3) * 5 + j];
#pragma unroll
    for (int off = 1; off < 64; off <<= 1) p += __shfl_xor(p, off);
    dots[j] = p;
  }
  if (lane == 0) {
#pragma unroll
    for (int j = 0; j < 5; ++j) out[(size_t)wid * 5 + j] = dots[j] + bout[j];
  }
}

// ---------------- host-side launch ----------------
extern "C" void kernel_launch(void* const* d_in, const int* in_sizes, int n_in,
                              void* d_out, int out_size, void* d_ws, size_t ws_size,
                              hipStream_t stream) {
  const float* x       = (const float*)d_in[0];
  const int*   ei      = (const int*)  d_in[1];
  const float* w_in    = (const float*)d_in[2];
  const float* b_in    = (const float*)d_in[3];
  const float* se_in_w = (const float*)d_in[4];
  const float* se_in_b = (const float*)d_in[5];
  const float* sage_w1 = (const float*)d_in[6];
  const float* sage_b1 = (const float*)d_in[7];
  const float* sage_w2 = (const float*)d_in[8];
  const float* sage_b2 = (const float*)d_in[9];
  const float* se_out_w= (const float*)d_in[10];
  const float* se_out_b= (const float*)d_in[11];
  const float* enc_w1  = (const float*)d_in[12];
  const float* enc_b1  = (const float*)d_in[13];
  const float* enc_w2  = (const float*)d_in[14];
  const float* enc_b2  = (const float*)d_in[15];
  const float* ln_g    = (const float*)d_in[16];
  const float* ln_b    = (const float*)d_in[17];
  const float* bdl_w1  = (const float*)d_in[18];
  const float* bdl_b1  = (const float*)d_in[19];
  const float* bdl_w2  = (const float*)d_in[20];
  const float* bdl_b2  = (const float*)d_in[21];
  const float* oln_g   = (const float*)d_in[22];
  const float* oln_b   = (const float*)d_in[23];
  const float* w_out   = (const float*)d_in[24];
  const float* b_out   = (const float*)d_in[25];
  float* out = (float*)d_out;

  const int HID = 256, SW = 512;
  const int N = in_sizes[0] / HID;   // 30000
  const int E = in_sizes[1] / 2;     // 480000

  // ---- workspace layout (~185 MB) ----
  float* ws = (float*)d_ws;
  float* h32 = ws;                              // [N,256] fp32 residual carrier (outer)
  float* o   = h32 + (size_t)N * HID;           // [N,256] rotation (c,s)*128
  unsigned short* h_bf = (unsigned short*)(o + (size_t)N * HID);  // [N,256]
  unsigned short* z_bf = h_bf + (size_t)N * HID;                  // [N,512] bf16 z carrier
  unsigned short* t_bf = z_bf + (size_t)N * SW;                   // [N,512]
  unsigned short* u_bf = t_bf + (size_t)N * SW;                   // [N,512]
  // weight transposes (bf16 [N,K])
  unsigned short* wts = u_bf + (size_t)N * SW;
  size_t off = 0;
  unsigned short* wt_in    = wts + off; off += 256 * 256;
  unsigned short* wt_se_in = wts + off; off += 512 * 256;
  unsigned short* wt_sage1 = wts + off; off += (size_t)5 * 512 * 1024;
  unsigned short* wt_sage2 = wts + off; off += (size_t)5 * 512 * 512;
  unsigned short* wt_se_out= wts + off; off += 512 * 512;
  unsigned short* wt_enc1  = wts + off; off += (size_t)2 * 512 * 512;
  unsigned short* wt_enc2  = wts + off; off += (size_t)2 * 512 * 512;
  unsigned short* wt_bdl1  = wts + off; off += (size_t)2 * 256 * 512;
  unsigned short* wt_bdl2  = wts + off; off += (size_t)2 * 256 * 256;
  int* deg  = (int*)(wts + off);
  int* rp   = deg + N;
  int* cur  = rp + N + 1;
  int* srcs = cur + N;
  size_t need = (size_t)((char*)(srcs + E) - (char*)d_ws);
  if (ws_size < need) return;

  // aliases (lifetime-disjoint)
  unsigned short* xbf = u_bf;                   // x cast, consumed by first GEMM
  unsigned short* hn  = z_bf;                   // after z consumed by se_out
  unsigned short* y   = z_bf + (size_t)N * HID;
  unsigned short* msg = t_bf;                   // nr consumed by k_oparams first
  unsigned short* g2  = u_bf;

  const int* esrc = ei;
  const int* edst = ei + E;

  auto cdiv = [](int a, int b) { return (a + b - 1) / b; };
  dim3 blk(256);
  int mb_cnt = cdiv(N, 128);                    // 235
  int mgrp = cdiv(mb_cnt, 8);                   // 30
  int g_g256 = mgrp * 8 * 2;                    // Nc=256 -> 480 blocks (padded)
  int g_g512 = mgrp * 8 * 4;                    // Nc=512 -> 960 blocks (padded)
  int gw = cdiv(N * 64, 256);
  int g_agg512 = 8 * 256;                       // 8 slices x 256 node-groups
  int g_agg256 = 4 * 256;                       // 4 slices

  // ---- CSR build ----
  hipMemsetAsync(deg, 0, sizeof(int) * N, stream);
  k_hist<<<cdiv(E, 256), blk, 0, stream>>>(edst, deg, E);
  k_scan<<<1, 1024, 0, stream>>>(deg, rp, cur, N);
  k_fill<<<cdiv(E, 256), blk, 0, stream>>>(esrc, edst, cur, srcs, E);

  // ---- weight transposes to bf16 (batched over blockIdx.y) ----
  auto wT = [&](const float* W, unsigned short* Wt, int K, int Nc, int cnt) {
    k_wT<<<dim3(cdiv(K * Nc, 256), cnt), blk, 0, stream>>>(W, Wt, K, Nc);
  };
  wT(w_in, wt_in, 256, 256, 1);
  wT(se_in_w, wt_se_in, 256, 512, 1);
  wT(sage_w1, wt_sage1, 1024, 512, 5);
  wT(sage_w2, wt_sage2, 512, 512, 5);
  wT(se_out_w, wt_se_out, 512, 512, 1);
  wT(enc_w1, wt_enc1, 512, 512, 2);
  wT(enc_w2, wt_enc2, 512, 512, 2);
  wT(bdl_w1, wt_bdl1, 512, 256, 2);
  wT(bdl_w2, wt_bdl2, 256, 256, 2);
  k_cast<<<cdiv(N * HID, 256), blk, 0, stream>>>(x, xbf, N * HID);

  // ---- h = gelu(x @ w_in + b_in) : fp32 + bf16 ----
  k_mfma<1, 0, false, true, true><<<g_g256, blk, 0, stream>>>(
      xbf, nullptr, 256, 0, wt_in, b_in, nullptr, nullptr, h32, h_bf, N, 256);

  for (int k = 0; k < 2; ++k) {
    // z = gelu(h @ se_in_w + b)   (bf16 carrier)
    k_mfma<1, 0, false, false, true><<<g_g512, blk, 0, stream>>>(
        h_bf, nullptr, 256, 0, wt_se_in, se_in_b, nullptr, nullptr, nullptr, z_bf, N, 512);
    for (int i = 0; i < 5; ++i) {
      k_agg2<512, 3, false><<<g_agg512, blk, 0, stream>>>(z_bf, rp, srcs, nullptr, t_bf, N);
      k_mfma<1, 0, true, false, true><<<g_g512, blk, 0, stream>>>(
          z_bf, t_bf, 512, 512, wt_sage1 + (size_t)i * 512 * 1024,
          sage_b1 + (size_t)i * SW, nullptr, nullptr, nullptr, u_bf, N, 512);
      k_mfma<0, 2, false, false, true><<<g_g512, blk, 0, stream>>>(
          u_bf, nullptr, 512, 0, wt_sage2 + (size_t)i * 512 * 512,
          sage_b2 + (size_t)i * SW, nullptr, z_bf, nullptr, z_bf, N, 512);
    }
    // enc = z @ se_out_w + b
    k_mfma<0, 0, false, false, true><<<g_g512, blk, 0, stream>>>(
        z_bf, nullptr, 512, 0, wt_se_out, se_out_b, nullptr, nullptr, nullptr, t_bf, N, 512);
    // nr = gelu(enc @ enc_w1 + b) @ enc_w2 + b
    k_mfma<1, 0, false, false, true><<<g_g512, blk, 0, stream>>>(
        t_bf, nullptr, 512, 0, wt_enc1 + (size_t)k * 512 * 512,
        enc_b1 + (size_t)k * SW, nullptr, nullptr, nullptr, u_bf, N, 512);
    k_mfma<0, 0, false, false, true><<<g_g512, blk, 0, stream>>>(
        u_bf, nullptr, 512, 0, wt_enc2 + (size_t)k * 512 * 512,
        enc_b2 + (size_t)k * SW, nullptr, nullptr, nullptr, t_bf, N, 512);
    // rotation params; hn=LN(h), y=O@hn; msg=O^T@mean(y)
    k_oparams<<<cdiv(N * 128, 256), blk, 0, stream>>>(t_bf, o, N * 128);
    k_ln_rot<<<gw, blk, 0, stream>>>(h32, o, ln_g + (size_t)k * HID, ln_b + (size_t)k * HID, hn, y, N);
    k_agg2<256, 2, true><<<g_agg256, blk, 0, stream>>>(y, rp, srcs, o, msg, N);
    // h = h + gelu([hn|msg] @ bdl_w1 + b1) @ bdl_w2 + b2
    k_mfma<1, 0, true, false, true><<<g_g256, blk, 0, stream>>>(
        hn, msg, 256, 256, wt_bdl1 + (size_t)k * 256 * 512,
        bdl_b1 + (size_t)k * HID, nullptr, nullptr, nullptr, g2, N, 256);
    k_mfma<0, 1, false, true, true><<<g_g256, blk, 0, stream>>>(
        g2, nullptr, 256, 0, wt_bdl2 + (size_t)k * 256 * 256,
        bdl_b2 + (size_t)k * HID, h32, nullptr, h32, h_bf, N, 256);
  }

  k_final<<<gw, blk, 0, stream>>>(h32, oln_g, oln_b, w_out, b_out, out, N);
}

// Round 9
// 2610.039 us; speedup vs baseline: 1.4003x; 1.0974x over previous
//
#include <hip/hip_runtime.h>
#include <hip/hip_bf16.h>
#include <cstdint>
#include <cstddef>

// N=30000 nodes, E=480000 edges, HID=256, SW=512, NB=128 bundles of dim 2.
// Householder(2x2) collapses to planar rotation: x=X[1,0]; c=(x^2-1)/(1+x^2), s=2x/(1+x^2).

typedef __attribute__((ext_vector_type(8))) short short8;
typedef __attribute__((ext_vector_type(4))) float f32x4;

__device__ __forceinline__ float gelu_exact(float x) {
  return 0.5f * x * (1.0f + erff(x * 0.7071067811865475f));
}
__device__ __forceinline__ unsigned short f2bf(float f) {
  __hip_bfloat16 b = __float2bfloat16(f);
  return *reinterpret_cast<unsigned short*>(&b);
}
__device__ __forceinline__ float bf2f(unsigned short u) {
  return __uint_as_float((unsigned)u << 16);
}
__device__ __forceinline__ float bflo(unsigned u) { return __uint_as_float(u << 16); }
__device__ __forceinline__ float bfhi(unsigned u) { return __uint_as_float(u & 0xffff0000u); }
__device__ __forceinline__ unsigned packbf(float f0, float f1) {
  return (unsigned)f2bf(f0) | ((unsigned)f2bf(f1) << 16);
}
__device__ __forceinline__ void gload16(const void* g, void* l) {
  __builtin_amdgcn_global_load_lds((const __attribute__((address_space(1))) void*)g,
                                   (__attribute__((address_space(3))) void*)l, 16, 0, 0);
}
#define SCHEDB() __builtin_amdgcn_sched_barrier(0)

// ---------------- CSR build ----------------
__global__ void k_hist(const int* __restrict__ dst, int* __restrict__ deg, int E) {
  int i = blockIdx.x * 256 + threadIdx.x;
  if (i < E) atomicAdd(&deg[dst[i]], 1);
}

__global__ __launch_bounds__(1024)
void k_scan(const int* __restrict__ deg, int* __restrict__ rp, int* __restrict__ cur, int Nn) {
  __shared__ int part[1024];
  int t = threadIdx.x;
  int chunk = (Nn + 1023) >> 10;
  int s0 = t * chunk;
  int e0 = s0 + chunk; if (e0 > Nn) e0 = Nn;
  int s = 0;
  for (int i = s0; i < e0; ++i) s += deg[i];
  part[t] = s;
  __syncthreads();
  for (int off = 1; off < 1024; off <<= 1) {
    int v = (t >= off) ? part[t - off] : 0;
    __syncthreads();
    part[t] += v;
    __syncthreads();
  }
  int base = (t == 0) ? 0 : part[t - 1];
  for (int i = s0; i < e0; ++i) {
    rp[i] = base; cur[i] = base; base += deg[i];
  }
  if (t == 0) rp[Nn] = part[1023];
}

__global__ void k_fill(const int* __restrict__ src, const int* __restrict__ dst,
                       int* __restrict__ cur, int* __restrict__ srcs, int E) {
  int i = blockIdx.x * 256 + threadIdx.x;
  if (i < E) {
    int p = atomicAdd(&cur[dst[i]], 1);
    srcs[p] = src[i];
  }
}

// ---------------- batched weight transpose fp32 [K,N] -> bf16 [N,K] ----------------
__global__ void k_wT(const float* __restrict__ W, unsigned short* __restrict__ Wt, int K, int Nc) {
  const float* Ws = W + (size_t)blockIdx.y * K * Nc;
  unsigned short* Wd = Wt + (size_t)blockIdx.y * K * Nc;
  int idx = blockIdx.x * 256 + threadIdx.x;
  if (idx >= K * Nc) return;
  int k = idx % K, n = idx / K;                       // k fastest -> coalesced writes
  Wd[(size_t)n * K + k] = f2bf(Ws[(size_t)k * Nc + n]);
}

__global__ void k_cast(const float* __restrict__ src, unsigned short* __restrict__ dst, int n) {
  int i = blockIdx.x * 256 + threadIdx.x;
  if (i < n) dst[i] = f2bf(src[i]);
}

// ---------------- bf16 MFMA GEMM: 128x128 tile, BK=64, 4 waves, double-buffered ----------------
// C = [R +] act(A @ W + bias), A bf16 row-major (dual-source concat along K),
// Wt = W^T bf16 [Nc, Ktot] row-major. fp32 accumulate. 64 KiB LDS -> 2 blocks/CU.
// Round-4-proven counted-vmcnt depth-2 schedule (no vmcnt(0) in steady state):
//   vmcnt(8); barrier          -> tile t staged & visible (t+1's 8 loads stay in flight)
//   ds_read 16 frags; lgkmcnt(0); barrier -> buffer free
//   stage(t+2) into freed buffer (DMA overlaps MFMA)
//   32 MFMA from registers
// XCD co-location: 1D padded grid, all n-blocks of an A-panel land on the same XCD.
// RES: 0=none, 1=fp32 residual, 2=bf16 residual. OP: write rotation params from epilogue.
template<int ACT, int RES, bool DUAL, bool W32, bool WBF, bool OP>
__global__ __launch_bounds__(256)
void k_mfma(const unsigned short* __restrict__ A1, const unsigned short* __restrict__ A2,
            int K1, int K2,
            const unsigned short* __restrict__ Wt, const float* __restrict__ bias,
            const float* R32, const unsigned short* Rbf,
            float* C32, unsigned short* Cbf, float* Op, int M, int Nc) {
  const int mb_cnt = (M + 127) >> 7;
  const int nb_cnt = Nc >> 7;
  int u = blockIdx.x;
  int xcd = u & 7;
  int rest = u >> 3;
  int nb = rest % nb_cnt;
  int mb = (rest / nb_cnt) * 8 + xcd;
  if (mb >= mb_cnt) return;
  const int m0 = mb << 7, n0 = nb << 7;

  __shared__ unsigned short As[2][128 * 64];   // [buf][row][64] bf16, 128B rows, swizzled segs
  __shared__ unsigned short Bs[2][128 * 64];
  const int tid = threadIdx.x;
  const int lane = tid & 63, wv = tid >> 6;
  const int wr = (wv >> 1) * 64, wc = (wv & 1) * 64;  // wave's 64x64 subtile
  const int rA = lane & 15, kg = lane >> 4;
  const int Ktot = K1 + K2;
  const int nt = Ktot >> 6;

  f32x4 acc[4][4];
#pragma unroll
  for (int m = 0; m < 4; ++m)
#pragma unroll
    for (int n = 0; n < 4; ++n)
#pragma unroll
      for (int r = 0; r < 4; ++r) acc[m][n][r] = 0.f;

  // stage K-tile t into buffer b: 1024 16B-chunks per matrix, 4 issues x 256 thr.
  // linear LDS dest; swizzle applied on the GLOBAL source k-segment (involution).
  auto stage = [&](int t, int b) {
    int k0 = t << 6;
    const unsigned short* Asrc; int kc, lda;
    if (!DUAL || k0 < K1) { Asrc = A1; kc = k0; lda = K1; }
    else                  { Asrc = A2; kc = k0 - K1; lda = K2; }
#pragma unroll
    for (int is = 0; is < 4; ++is) {
      int chunk = is * 256 + tid;
      int row = chunk >> 3, seg = chunk & 7;
      int ks = seg ^ (row & 7);
      int gm = m0 + row; gm = gm < M ? gm : M - 1;
      gload16(Asrc + (size_t)gm * lda + kc + ks * 8, (char*)As[b] + (size_t)chunk * 16);
      gload16(Wt + (size_t)(n0 + row) * Ktot + k0 + ks * 8, (char*)Bs[b] + (size_t)chunk * 16);
    }
  };

  stage(0, 0);
  if (nt > 1) stage(1, 1);

  for (int t = 0; t < nt; ++t) {
    const int b = t & 1;
    // tile t's own loads complete; tile t+1's 8 loads may stay in flight
    if (t + 1 < nt) asm volatile("s_waitcnt vmcnt(8)" ::: "memory");
    else            asm volatile("s_waitcnt vmcnt(0)" ::: "memory");
    SCHEDB();
    __builtin_amdgcn_s_barrier();
    SCHEDB();

    short8 af[2][4], bq[2][4];
#pragma unroll
    for (int kk = 0; kk < 2; ++kk) {
#pragma unroll
      for (int m = 0; m < 4; ++m) {
        int row = wr + m * 16 + rA;
        int ks = (kk * 4 + kg) ^ (row & 7);
        af[kk][m] = *reinterpret_cast<const short8*>((const char*)As[b] + row * 128 + ks * 16);
      }
#pragma unroll
      for (int n = 0; n < 4; ++n) {
        int col = wc + n * 16 + rA;
        int ks = (kk * 4 + kg) ^ (col & 7);
        bq[kk][n] = *reinterpret_cast<const short8*>((const char*)Bs[b] + col * 128 + ks * 16);
      }
    }
    asm volatile("s_waitcnt lgkmcnt(0)" ::: "memory");
    SCHEDB();
    __builtin_amdgcn_s_barrier();   // all waves done reading buf b
    SCHEDB();
    if (t + 2 < nt) stage(t + 2, b);  // DMA into freed buffer, overlaps MFMA

    __builtin_amdgcn_s_setprio(1);
#pragma unroll
    for (int kk = 0; kk < 2; ++kk)
#pragma unroll
      for (int m = 0; m < 4; ++m)
#pragma unroll
        for (int n = 0; n < 4; ++n)
          acc[m][n] = __builtin_amdgcn_mfma_f32_16x16x32_bf16(af[kk][m], bq[kk][n],
                                                              acc[m][n], 0, 0, 0);
    __builtin_amdgcn_s_setprio(0);
  }

  // epilogue: C/D layout col=lane&15, row=(lane>>4)*4+reg  [m89]
#pragma unroll
  for (int m = 0; m < 4; ++m) {
    int gr0 = m0 + wr + m * 16 + kg * 4;
#pragma unroll
    for (int n = 0; n < 4; ++n) {
      int gc = n0 + wc + n * 16 + rA;
      float bv = bias[gc];
#pragma unroll
      for (int r = 0; r < 4; ++r) {
        int gr = gr0 + r;
        if (gr < M) {
          float v = acc[m][n][r] + bv;
          if (ACT == 1) v = gelu_exact(v);
          if (RES == 1) v += R32[(size_t)gr * Nc + gc];
          if (RES == 2) v += bf2f(Rbf[(size_t)gr * Nc + gc]);
          if (W32) C32[(size_t)gr * Nc + gc] = v;
          if (WBF) Cbf[(size_t)gr * Nc + gc] = f2bf(v);
          if (OP) {
            // nr column 4b+2 -> rotation (c,s) for bundle b = gc>>2
            if ((rA & 3) == 2) {
              float iv = 1.0f / (1.0f + v * v);
              float* op = Op + (size_t)gr * 256 + ((gc >> 2) << 1);
              op[0] = (v * v - 1.0f) * iv;
              op[1] = 2.0f * v * iv;
            }
          }
        }
      }
    }
  }
}

// ---------------- mean aggregation over bf16 rows (one wave per node; round-6 proven) ----------------
template<int W, bool ROT>
__global__ __launch_bounds__(256)
void k_agg(const unsigned short* __restrict__ X, const int* __restrict__ rp,
           const int* __restrict__ srcs, const float* __restrict__ o,
           unsigned short* __restrict__ out, int Nn) {
  int wid = (blockIdx.x * 256 + threadIdx.x) >> 6;
  int lane = threadIdx.x & 63;
  if (wid >= Nn) return;
  constexpr int PE = W / 64;    // bf16 elems per lane: 8 (W=512) or 4 (W=256)
  float a[PE];
#pragma unroll
  for (int p = 0; p < PE; ++p) a[p] = 0.f;
  int beg = rp[wid], end = rp[wid + 1];
  for (int e = beg; e < end; ++e) {
    int s = srcs[e];
    const unsigned* row = reinterpret_cast<const unsigned*>(X + (size_t)s * W) + lane * (PE / 2);
    if (PE == 8) {
      uint4 v = *reinterpret_cast<const uint4*>(row);
      a[0] += bflo(v.x); a[1] += bfhi(v.x); a[2] += bflo(v.y); a[3] += bfhi(v.y);
      a[4] += bflo(v.z); a[5] += bfhi(v.z); a[6] += bflo(v.w); a[7] += bfhi(v.w);
    } else {
      uint2 v = *reinterpret_cast<const uint2*>(row);
      a[0] += bflo(v.x); a[1] += bfhi(v.x); a[2] += bflo(v.y); a[3] += bfhi(v.y);
    }
  }
  float inv = (end > beg) ? 1.0f / (float)(end - beg) : 0.0f;
#pragma unroll
  for (int p = 0; p < PE; ++p) a[p] *= inv;
  if (ROT) {
    float4 oc = *reinterpret_cast<const float4*>(o + (size_t)wid * 256 + lane * 4); // c0,s0,c1,s1
    float m0 = oc.x * a[0] - oc.y * a[1];
    float m1 = oc.y * a[0] + oc.x * a[1];
    float m2 = oc.z * a[2] - oc.w * a[3];
    float m3 = oc.w * a[2] + oc.z * a[3];
    a[0] = m0; a[1] = m1; a[2] = m2; a[3] = m3;
  }
  unsigned short* op = out + (size_t)wid * W + lane * PE;
  if (PE == 8) {
    uint4 rv;
    rv.x = packbf(a[0], a[1]); rv.y = packbf(a[2], a[3]);
    rv.z = packbf(a[4], a[5]); rv.w = packbf(a[6], a[7]);
    *reinterpret_cast<uint4*>(op) = rv;
  } else {
    uint2 rv;
    rv.x = packbf(a[0], a[1]); rv.y = packbf(a[2], a[3]);
    *reinterpret_cast<uint2*>(op) = rv;
  }
}

// ---------------- LayerNorm + rotate-into-frame; bf16 outputs ----------------
__global__ __launch_bounds__(256)
void k_ln_rot(const float* __restrict__ h, const float* __restrict__ o,
              const float* __restrict__ g, const float* __restrict__ b,
              unsigned short* __restrict__ hn, unsigned short* __restrict__ y, int Nn) {
  int wid = (blockIdx.x * 256 + threadIdx.x) >> 6;
  int lane = threadIdx.x & 63;
  if (wid >= Nn) return;
  float4 v = reinterpret_cast<const float4*>(h + (size_t)wid * 256)[lane];
  float s = v.x + v.y + v.z + v.w;
  float ss = v.x * v.x + v.y * v.y + v.z * v.z + v.w * v.w;
#pragma unroll
  for (int off = 1; off < 64; off <<= 1) { s += __shfl_xor(s, off); ss += __shfl_xor(ss, off); }
  float mean = s * (1.0f / 256.0f);
  float var = ss * (1.0f / 256.0f) - mean * mean;
  float rs = rsqrtf(var + 1e-5f);
  float4 gg = reinterpret_cast<const float4*>(g)[lane];
  float4 bb = reinterpret_cast<const float4*>(b)[lane];
  float h0 = (v.x - mean) * rs * gg.x + bb.x;
  float h1 = (v.y - mean) * rs * gg.y + bb.y;
  float h2 = (v.z - mean) * rs * gg.z + bb.z;
  float h3 = (v.w - mean) * rs * gg.w + bb.w;
  uint2 hv; hv.x = packbf(h0, h1); hv.y = packbf(h2, h3);
  *reinterpret_cast<uint2*>(hn + (size_t)wid * 256 + lane * 4) = hv;
  float4 oc = *reinterpret_cast<const float4*>(o + (size_t)wid * 256 + lane * 4); // c0,s0,c1,s1
  float y0 =  oc.x * h0 + oc.y * h1;
  float y1 = -oc.y * h0 + oc.x * h1;
  float y2 =  oc.z * h2 + oc.w * h3;
  float y3 = -oc.w * h2 + oc.z * h3;
  uint2 yv; yv.x = packbf(y0, y1); yv.y = packbf(y2, y3);
  *reinterpret_cast<uint2*>(y + (size_t)wid * 256 + lane * 4) = yv;
}

// ---------------- final: out = LN(h) @ w_out + b_out ----------------
__global__ __launch_bounds__(256)
void k_final(const float* __restrict__ h, const float* __restrict__ g,
             const float* __restrict__ b, const float* __restrict__ wout,
             const float* __restrict__ bout, float* __restrict__ out, int Nn) {
  int wid = (blockIdx.x * 256 + threadIdx.x) >> 6;
  int lane = threadIdx.x & 63;
  if (wid >= Nn) return;
  float4 v = reinterpret_cast<const float4*>(h + (size_t)wid * 256)[lane];
  float s = v.x + v.y + v.z + v.w;
  float ss = v.x * v.x + v.y * v.y + v.z * v.z + v.w * v.w;
#pragma unroll
  for (int off = 1; off < 64; off <<= 1) { s += __shfl_xor(s, off); ss += __shfl_xor(ss, off); }
  float mean = s * (1.0f / 256.0f);
  float var = ss * (1.0f / 256.0f) - mean * mean;
  float rs = rsqrtf(var + 1e-5f);
  float4 gg = reinterpret_cast<const float4*>(g)[lane];
  float4 bb = reinterpret_cast<const float4*>(b)[lane];
  float hv[4];
  hv[0] = (v.x - mean) * rs * gg.x + bb.x;
  hv[1] = (v.y - mean) * rs * gg.y + bb.y;
  hv[2] = (v.z - mean) * rs * gg.z + bb.z;
  hv[3] = (v.w - mean) * rs * gg.w + bb.w;
  int c0 = lane * 4;
  float dots[5];
#pragma unroll
  for (int j = 0; j < 5; ++j) {
    float p = hv[0] * wout[(size_t)(c0 + 0) * 5 + j] + hv[1] * wout[(size_t)(c0 + 1) * 5 + j]
            + hv[2] * wout[(size_t)(c0 + 2) * 5 + j] + hv[3] * wout[(size_t)(c0 + 3) * 5 + j];
#pragma unroll
    for (int off = 1; off < 64; off <<= 1) p += __shfl_xor(p, off);
    dots[j] = p;
  }
  if (lane == 0) {
#pragma unroll
    for (int j = 0; j < 5; ++j) out[(size_t)wid * 5 + j] = dots[j] + bout[j];
  }
}

// ---------------- host-side launch ----------------
extern "C" void kernel_launch(void* const* d_in, const int* in_sizes, int n_in,
                              void* d_out, int out_size, void* d_ws, size_t ws_size,
                              hipStream_t stream) {
  const float* x       = (const float*)d_in[0];
  const int*   ei      = (const int*)  d_in[1];
  const float* w_in    = (const float*)d_in[2];
  const float* b_in    = (const float*)d_in[3];
  const float* se_in_w = (const float*)d_in[4];
  const float* se_in_b = (const float*)d_in[5];
  const float* sage_w1 = (const float*)d_in[6];
  const float* sage_b1 = (const float*)d_in[7];
  const float* sage_w2 = (const float*)d_in[8];
  const float* sage_b2 = (const float*)d_in[9];
  const float* se_out_w= (const float*)d_in[10];
  const float* se_out_b= (const float*)d_in[11];
  const float* enc_w1  = (const float*)d_in[12];
  const float* enc_b1  = (const float*)d_in[13];
  const float* enc_w2  = (const float*)d_in[14];
  const float* enc_b2  = (const float*)d_in[15];
  const float* ln_g    = (const float*)d_in[16];
  const float* ln_b    = (const float*)d_in[17];
  const float* bdl_w1  = (const float*)d_in[18];
  const float* bdl_b1  = (const float*)d_in[19];
  const float* bdl_w2  = (const float*)d_in[20];
  const float* bdl_b2  = (const float*)d_in[21];
  const float* oln_g   = (const float*)d_in[22];
  const float* oln_b   = (const float*)d_in[23];
  const float* w_out   = (const float*)d_in[24];
  const float* b_out   = (const float*)d_in[25];
  float* out = (float*)d_out;

  const int HID = 256, SW = 512;
  const int N = in_sizes[0] / HID;   // 30000
  const int E = in_sizes[1] / 2;     // 480000

  // ---- workspace layout (~185 MB) ----
  float* ws = (float*)d_ws;
  float* h32 = ws;                              // [N,256] fp32 residual carrier (outer)
  float* o   = h32 + (size_t)N * HID;           // [N,256] rotation (c,s)*128
  unsigned short* h_bf = (unsigned short*)(o + (size_t)N * HID);  // [N,256]
  unsigned short* z_bf = h_bf + (size_t)N * HID;                  // [N,512] bf16 z carrier
  unsigned short* t_bf = z_bf + (size_t)N * SW;                   // [N,512]
  unsigned short* u_bf = t_bf + (size_t)N * SW;                   // [N,512]
  // weight transposes (bf16 [N,K])
  unsigned short* wts = u_bf + (size_t)N * SW;
  size_t off = 0;
  unsigned short* wt_in    = wts + off; off += 256 * 256;
  unsigned short* wt_se_in = wts + off; off += 512 * 256;
  unsigned short* wt_sage1 = wts + off; off += (size_t)5 * 512 * 1024;
  unsigned short* wt_sage2 = wts + off; off += (size_t)5 * 512 * 512;
  unsigned short* wt_se_out= wts + off; off += 512 * 512;
  unsigned short* wt_enc1  = wts + off; off += (size_t)2 * 512 * 512;
  unsigned short* wt_enc2  = wts + off; off += (size_t)2 * 512 * 512;
  unsigned short* wt_bdl1  = wts + off; off += (size_t)2 * 256 * 512;
  unsigned short* wt_bdl2  = wts + off; off += (size_t)2 * 256 * 256;
  int* deg  = (int*)(wts + off);
  int* rp   = deg + N;
  int* cur  = rp + N + 1;
  int* srcs = cur + N;
  size_t need = (size_t)((char*)(srcs + E) - (char*)d_ws);
  if (ws_size < need) return;

  // aliases (lifetime-disjoint)
  unsigned short* xbf = u_bf;                   // x cast, consumed by first GEMM
  unsigned short* hn  = z_bf;                   // after z consumed by se_out
  unsigned short* y   = z_bf + (size_t)N * HID;
  unsigned short* msg = t_bf;
  unsigned short* g2  = u_bf;

  const int* esrc = ei;
  const int* edst = ei + E;

  auto cdiv = [](int a, int b) { return (a + b - 1) / b; };
  dim3 blk(256);
  int mb_cnt = cdiv(N, 128);                    // 235
  int mgrp = cdiv(mb_cnt, 8);                   // 30
  int g_g256 = mgrp * 8 * 2;                    // Nc=256 -> 480 blocks (padded)
  int g_g512 = mgrp * 8 * 4;                    // Nc=512 -> 960 blocks (padded)
  int gw = cdiv(N * 64, 256);

  // ---- CSR build ----
  hipMemsetAsync(deg, 0, sizeof(int) * N, stream);
  k_hist<<<cdiv(E, 256), blk, 0, stream>>>(edst, deg, E);
  k_scan<<<1, 1024, 0, stream>>>(deg, rp, cur, N);
  k_fill<<<cdiv(E, 256), blk, 0, stream>>>(esrc, edst, cur, srcs, E);

  // ---- weight transposes to bf16 (batched over blockIdx.y) ----
  auto wT = [&](const float* W, unsigned short* Wt, int K, int Nc, int cnt) {
    k_wT<<<dim3(cdiv(K * Nc, 256), cnt), blk, 0, stream>>>(W, Wt, K, Nc);
  };
  wT(w_in, wt_in, 256, 256, 1);
  wT(se_in_w, wt_se_in, 256, 512, 1);
  wT(sage_w1, wt_sage1, 1024, 512, 5);
  wT(sage_w2, wt_sage2, 512, 512, 5);
  wT(se_out_w, wt_se_out, 512, 512, 1);
  wT(enc_w1, wt_enc1, 512, 512, 2);
  wT(enc_w2, wt_enc2, 512, 512, 2);
  wT(bdl_w1, wt_bdl1, 512, 256, 2);
  wT(bdl_w2, wt_bdl2, 256, 256, 2);
  k_cast<<<cdiv(N * HID, 256), blk, 0, stream>>>(x, xbf, N * HID);

  // ---- h = gelu(x @ w_in + b_in) : fp32 + bf16 ----
  k_mfma<1, 0, false, true, true, false><<<g_g256, blk, 0, stream>>>(
      xbf, nullptr, 256, 0, wt_in, b_in, nullptr, nullptr, h32, h_bf, nullptr, N, 256);

  for (int k = 0; k < 2; ++k) {
    // z = gelu(h @ se_in_w + b)   (bf16 carrier)
    k_mfma<1, 0, false, false, true, false><<<g_g512, blk, 0, stream>>>(
        h_bf, nullptr, 256, 0, wt_se_in, se_in_b, nullptr, nullptr, nullptr, z_bf, nullptr, N, 512);
    for (int i = 0; i < 5; ++i) {
      k_agg<512, false><<<gw, blk, 0, stream>>>(z_bf, rp, srcs, nullptr, t_bf, N);
      k_mfma<1, 0, true, false, true, false><<<g_g512, blk, 0, stream>>>(
          z_bf, t_bf, 512, 512, wt_sage1 + (size_t)i * 512 * 1024,
          sage_b1 + (size_t)i * SW, nullptr, nullptr, nullptr, u_bf, nullptr, N, 512);
      k_mfma<0, 2, false, false, true, false><<<g_g512, blk, 0, stream>>>(
          u_bf, nullptr, 512, 0, wt_sage2 + (size_t)i * 512 * 512,
          sage_b2 + (size_t)i * SW, nullptr, z_bf, nullptr, z_bf, nullptr, N, 512);
    }
    // enc = z @ se_out_w + b
    k_mfma<0, 0, false, false, true, false><<<g_g512, blk, 0, stream>>>(
        z_bf, nullptr, 512, 0, wt_se_out, se_out_b, nullptr, nullptr, nullptr, t_bf, nullptr, N, 512);
    // nr = gelu(enc @ enc_w1 + b) @ enc_w2 + b ; rotation params fused into enc2 epilogue
    k_mfma<1, 0, false, false, true, false><<<g_g512, blk, 0, stream>>>(
        t_bf, nullptr, 512, 0, wt_enc1 + (size_t)k * 512 * 512,
        enc_b1 + (size_t)k * SW, nullptr, nullptr, nullptr, u_bf, nullptr, N, 512);
    k_mfma<0, 0, false, false, false, true><<<g_g512, blk, 0, stream>>>(
        u_bf, nullptr, 512, 0, wt_enc2 + (size_t)k * 512 * 512,
        enc_b2 + (size_t)k * SW, nullptr, nullptr, nullptr, nullptr, o, N, 512);
    // hn=LN(h), y=O@hn; msg=O^T@mean(y)
    k_ln_rot<<<gw, blk, 0, stream>>>(h32, o, ln_g + (size_t)k * HID, ln_b + (size_t)k * HID, hn, y, N);
    k_agg<256, true><<<gw, blk, 0, stream>>>(y, rp, srcs, o, msg, N);
    // h = h + gelu([hn|msg] @ bdl_w1 + b1) @ bdl_w2 + b2
    k_mfma<1, 0, true, false, true, false><<<g_g256, blk, 0, stream>>>(
        hn, msg, 256, 256, wt_bdl1 + (size_t)k * 256 * 512,
        bdl_b1 + (size_t)k * HID, nullptr, nullptr, nullptr, g2, nullptr, N, 256);
    k_mfma<0, 1, false, true, true, false><<<g_g256, blk, 0, stream>>>(
        g2, nullptr, 256, 0, wt_bdl2 + (size_t)k * 256 * 256,
        bdl_b2 + (size_t)k * HID, h32, nullptr, h32, h_bf, nullptr, N, 256);
  }

  k_final<<<gw, blk, 0, stream>>>(h32, oln_g, oln_b, w_out, b_out, out, N);
}